// Round 9
// baseline (3606.900 us; speedup 1.0000x reference)
//
#include <hip/hip_runtime.h>
#include <hip/hip_bf16.h>
#include <math.h>

typedef __hip_bfloat16 bf16;
typedef __attribute__((ext_vector_type(8))) short short8;
typedef __attribute__((ext_vector_type(4))) short short4v;
typedef __attribute__((ext_vector_type(4))) float f32x4;

// problem dims
#define B_    64
#define T_    512
#define D_    128
#define N_    510
#define H_    512
#define TOK_  384
#define PRED1_ 12533760L  // B_*N_*TOK_
#define TOKOFF_ 37601280L // 3*PRED1_ : tokens offset in d_out (floats)

// ---- workspace layout (bytes) ----
#define O_XBF  0UL            // x bf16            8,388,608
#define O_SWB  8388608UL      // sess_W bf16         524,288
#define O_PW   8912896UL      // proj_W bf16         393,216
#define O_WIH  9306112UL      // gru_Wih bf16      1,572,864
#define O_WHH  10878976UL     // gru_Whh bf16      1,572,864
#define O_W1   12451840UL     // head_W1 bf16      1,572,864
#define O_W2   14024704UL     // head_W2 bf16      1,179,648
#define O_TOK  15204352UL     // tokens bf16      25,067,520  rows [n*64+b]
#define O_HBF  40271872UL     // h bf16 (post-RMS)33,423,360
#define O_HID  73695232UL     // hidden bf16      33,423,360  rows [s*64+b]
#define O_ABF  107118592UL    // gelu act bf16
#define O_GX   140541952UL    // gx bf16 100,270,080 (h_pre fp32 overlapped first)

#define HID_BYTES 33423360UL

// ---------------- fp32 -> bf16 convert ----------------
__global__ void k_f2b(const float* __restrict__ s, bf16* __restrict__ d, int n4) {
  int i = blockIdx.x * 256 + threadIdx.x;
  if (i < n4) {
    float4 v = ((const float4*)s)[i];
    union { short4v sv; bf16 h[4]; } u;
    u.h[0] = __float2bfloat16(v.x); u.h[1] = __float2bfloat16(v.y);
    u.h[2] = __float2bfloat16(v.z); u.h[3] = __float2bfloat16(v.w);
    ((short4v*)d)[i] = u.sv;
  }
}

// ---------------- generic bf16 MFMA GEMM: C = A[M,K] @ W[N,K]^T + bias ----------------
enum { EPI_F32 = 0, EPI_BF16 = 1, EPI_GELU = 2, EPI_TOK = 3, EPI_F32R = 4 };
#define SLDA 40

template <int EPI>
__global__ __launch_bounds__(256, 2) void k_gemm(
    const bf16* __restrict__ A, const bf16* __restrict__ W,
    const float* __restrict__ bias, void* __restrict__ C,
    int K, int ldc, long zA, long zW, long zB, long zC,
    const int* __restrict__ sidx, float* __restrict__ tokf, bf16* __restrict__ tokb)
{
  const int tid = threadIdx.x;
  const int bm = blockIdx.x, bn = blockIdx.y, z = blockIdx.z;
  const int wsel = (EPI == EPI_TOK) ? sidx[z] : z;
  const int lane = tid & 63, wave = tid >> 6;
  const int wm = (wave & 1) << 6, wn = (wave >> 1) << 6;
  const int r16 = lane & 15, quad = lane >> 4;

  __shared__ bf16 sA[128 * SLDA];
  __shared__ bf16 sB[128 * SLDA];

  const bf16* Ag = A + (long)z * zA + (long)bm * 128 * K;
  const bf16* Wg = W + (long)wsel * zW + (long)bn * 128 * K;

  f32x4 zf = {0.f, 0.f, 0.f, 0.f};
  f32x4 acc[4][4];
  for (int i = 0; i < 4; ++i) for (int j = 0; j < 4; ++j) acc[i][j] = zf;

  const int sr = tid >> 1, sc = (tid & 1) << 4;
  for (int k0 = 0; k0 < K; k0 += 32) {
    *(short8*)&sA[sr*SLDA + sc]     = *(const short8*)&Ag[(long)sr*K + k0 + sc];
    *(short8*)&sA[sr*SLDA + sc + 8] = *(const short8*)&Ag[(long)sr*K + k0 + sc + 8];
    *(short8*)&sB[sr*SLDA + sc]     = *(const short8*)&Wg[(long)sr*K + k0 + sc];
    *(short8*)&sB[sr*SLDA + sc + 8] = *(const short8*)&Wg[(long)sr*K + k0 + sc + 8];
    __syncthreads();
    short8 fa[4], fb[4];
    for (int i = 0; i < 4; ++i) fa[i] = *(const short8*)&sA[(wm + i*16 + r16)*SLDA + quad*8];
    for (int j = 0; j < 4; ++j) fb[j] = *(const short8*)&sB[(wn + j*16 + r16)*SLDA + quad*8];
    for (int i = 0; i < 4; ++i)
      for (int j = 0; j < 4; ++j)
        acc[i][j] = __builtin_amdgcn_mfma_f32_16x16x32_bf16(fa[i], fb[j], acc[i][j], 0, 0, 0);
    __syncthreads();
  }

  const float* bz = bias + (long)wsel * zB + bn * 128;
  for (int i = 0; i < 4; ++i) {
    for (int j = 0; j < 4; ++j) {
      const int colL = wn + j*16 + r16;
      const float bv = bz[colL];
      for (int r = 0; r < 4; ++r) {
        float v = acc[i][j][r] + bv;
        const long grow = (long)bm*128 + wm + i*16 + quad*4 + r;
        const long gcol = (long)bn*128 + colL;
        if (EPI == EPI_F32) {
          ((float*)C)[(long)z*zC + grow*ldc + gcol] = v;
        } else if (EPI == EPI_BF16) {
          ((bf16*)C)[(long)z*zC + grow*ldc + gcol] = __float2bfloat16(v);
        } else if (EPI == EPI_GELU) {
          v = 0.5f * v * (1.0f + erff(v * 0.70710678118654752f));
          ((bf16*)C)[(long)z*zC + grow*ldc + gcol] = __float2bfloat16(v);
        } else if (EPI == EPI_F32R) {
          // rows are [n*64+b]; output wants [b*510+n]
          const long rb = grow & 63, rn = grow >> 6;
          ((float*)C)[(rb*510 + rn)*ldc + gcol] = v;
        } else { // EPI_TOK: z=batch, grow=t, gcol=e
          for (int p = 0; p < 3; ++p) {
            long n = grow - p;
            if (n >= 0 && n < N_) {
              tokf[((long)z*N_ + n)*TOK_ + gcol*3 + p] = v;                 // d_out: [b][n][tok]
              tokb[((long)n*B_ + z)*TOK_ + gcol*3 + p] = __float2bfloat16(v); // ws: rows [n*64+b]
            }
          }
        }
      }
    }
  }
}

// ---------------- RMSNorm rows of 512: fp32 in -> bf16 out ----------------
__global__ __launch_bounds__(256) void k_rms(const float* __restrict__ hpre,
                                             const float* __restrict__ scale,
                                             bf16* __restrict__ hbf)
{
  const int wave = threadIdx.x >> 6, lane = threadIdx.x & 63;
  const long row = (long)blockIdx.x * 4 + wave;
  const float* p = hpre + row * 512 + lane * 8;
  float4 v0 = *(const float4*)p;
  float4 v1 = *(const float4*)(p + 4);
  float ss = v0.x*v0.x + v0.y*v0.y + v0.z*v0.z + v0.w*v0.w
           + v1.x*v1.x + v1.y*v1.y + v1.z*v1.z + v1.w*v1.w;
  for (int m = 32; m >= 1; m >>= 1) ss += __shfl_xor(ss, m, 64);
  const float inv = 1.0f / sqrtf(ss * (1.0f/512.0f) + 1e-6f);
  const float* sc = scale + lane * 8;
  union { short8 sv; bf16 h[8]; } u;
  u.h[0] = __float2bfloat16(v0.x*inv*sc[0]); u.h[1] = __float2bfloat16(v0.y*inv*sc[1]);
  u.h[2] = __float2bfloat16(v0.z*inv*sc[2]); u.h[3] = __float2bfloat16(v0.w*inv*sc[3]);
  u.h[4] = __float2bfloat16(v1.x*inv*sc[4]); u.h[5] = __float2bfloat16(v1.y*inv*sc[5]);
  u.h[6] = __float2bfloat16(v1.z*inv*sc[6]); u.h[7] = __float2bfloat16(v1.w*inv*sc[7]);
  *(short8*)(hbf + row * 512 + lane * 8) = u.sv;
}

// ---------------- GRU: dual-group interleaved flagless scan ----------------
// r8 lesson: no unverifiable coherence fast paths -> pure r7 protocol (sentinel,
// sc1 both sides, device-proven). NEW: each wave serves TWO independent batch
// groups (A = batches 16p..16p+8, B = +8) in alternating phases. Group A's
// speculative DMA is issued at the end of A's phase and consumed only after
// B's full compute phase (~1500cy later): the L3 round trip AND the other
// producers' store-visibility window hide under sister-group compute.
// Counted wait: vmcnt(24) (sister phase issues exactly 4 stores + 12 gx loads
// + 8 DMAs after our DMA; vmcnt decrements in order -> <=24 outstanding means
// our 8-burst DMA landed). Miscounts are SAFE: hp is sentinel-refilled before
// each DMA issue, so an early read sees LDS sentinel -> retry with vmcnt(0).
// 128 WGs x 64 thr; weights LDS shared by both groups (same columns).
#define KP 520   // LDS row pad (elems)

// aux=16 == CPol SC1 on gfx950: device-scope load (coherent past L2) -- r7-proven
#define GL2LDS(g, l) __builtin_amdgcn_global_load_lds( \
    (const __attribute__((address_space(1))) void*)(g), \
    (__attribute__((address_space(3))) void*)(l), 16, 0, 16)

// One group-phase. HP = LDS h_prev buffer, B0 = batch base, GR/GZ/GN = gx regs,
// HC = own-col h regs. Uses s, lane, c16, quad, brv, hwv, wlds, bhr/bhz/bhn,
// hidden, gx, sentv from the enclosing scope.
#define GRU_PHASE(HP, B0, GR, GZ, GN, HC)                                        \
  {                                                                              \
    f32x4 ar = {0.f,0.f,0.f,0.f}, az = {0.f,0.f,0.f,0.f}, an = {0.f,0.f,0.f,0.f};\
    if (s > 0) {                                                                 \
      union AU { unsigned u[4]; short8 s8; } au[16];                             \
      asm volatile("s_waitcnt vmcnt(24)" ::: "memory");                          \
      while (true) {                                                             \
        unsigned mx = 0u;                                                        \
        _Pragma("unroll")                                                        \
        for (int kt = 0; kt < 16; ++kt) {                                        \
          au[kt].s8 = *(const short8*)&HP[(c16 & 7)*KP + kt*32 + quad*8];        \
          unsigned m01 = au[kt].u[0] > au[kt].u[1] ? au[kt].u[0] : au[kt].u[1];  \
          unsigned m23 = au[kt].u[2] > au[kt].u[3] ? au[kt].u[2] : au[kt].u[3];  \
          unsigned m = m01 > m23 ? m01 : m23;                                    \
          mx = mx > m ? mx : m;                                                  \
        }                                                                        \
        if (__all(mx != 0xFFFFFFFFu)) break;                                     \
        const bf16* rsrc = hidden + ((long)(s-1)*64 + (B0))*512 + lane*8;        \
        _Pragma("unroll")                                                        \
        for (int b = 0; b < 8; ++b) GL2LDS(rsrc + b*512, &HP[b*KP]);             \
        asm volatile("s_waitcnt vmcnt(0)" ::: "memory");                         \
      }                                                                          \
      _Pragma("unroll")                                                          \
      for (int kt = 0; kt < 16; ++kt) {                                          \
        short8 fr = *(const short8*)&wlds[((kt*3 + 0)*64 + lane)*8];             \
        short8 fz = *(const short8*)&wlds[((kt*3 + 1)*64 + lane)*8];             \
        short8 fn = *(const short8*)&wlds[((kt*3 + 2)*64 + lane)*8];             \
        ar = __builtin_amdgcn_mfma_f32_16x16x32_bf16(au[kt].s8, fr, ar, 0, 0, 0);\
        az = __builtin_amdgcn_mfma_f32_16x16x32_bf16(au[kt].s8, fz, az, 0, 0, 0);\
        an = __builtin_amdgcn_mfma_f32_16x16x32_bf16(au[kt].s8, fn, an, 0, 0, 0);\
      }                                                                          \
    }                                                                            \
    if (quad < 2) {                                                              \
      _Pragma("unroll")                                                          \
      for (int i2 = 0; i2 < 4; ++i2) {                                           \
        const float r  = 1.0f / (1.0f + expf(-(GR[i2] + ar[i2] + bhr)));         \
        const float z  = 1.0f / (1.0f + expf(-(GZ[i2] + az[i2] + bhz)));         \
        const float nn = tanhf(GN[i2] + r * (an[i2] + bhn));                     \
        const float hn = (1.0f - z)*nn + z*HC[i2];                               \
        union { bf16 h; unsigned short u; } cb; cb.h = __float2bfloat16(hn);     \
        HC[i2] = __bfloat162float(cb.h);                                         \
        unsigned mine = cb.u;                                                    \
        unsigned part = (unsigned)__shfl_xor((int)mine, 1, 64);                  \
        if (!(c16 & 1)) {                                                        \
          unsigned w = (part << 16) | mine;                                      \
          __hip_atomic_store(                                                    \
              (unsigned*)(hidden + ((long)s*64 + (B0) + brv + i2)*512 + hwv + c16),\
              w, __ATOMIC_RELAXED, __HIP_MEMORY_SCOPE_AGENT);                    \
        }                                                                        \
      }                                                                          \
    }                                                                            \
    if (s < 509) {                                                               \
      /* sentinel-refill hp (au safely in regs); guards any vmcnt miscount */    \
      asm volatile("s_waitcnt lgkmcnt(0)" ::: "memory");                         \
      _Pragma("unroll")                                                          \
      for (int b = 0; b < 8; ++b) *(short8*)&HP[b*KP + lane*8] = sentv;          \
      asm volatile("s_waitcnt lgkmcnt(0)" ::: "memory");                         \
      /* gx prefetch for s+1 (12 loads; complete under sister phase) */          \
      const bf16* gxs = gx + ((long)(s+1)*64 + (B0))*1536 + hwv + c16;           \
      _Pragma("unroll")                                                          \
      for (int i2 = 0; i2 < 4; ++i2) {                                           \
        const long ro = (long)(brv + i2) * 1536;                                 \
        GR[i2] = __bfloat162float(gxs[ro]);                                      \
        GZ[i2] = __bfloat162float(gxs[ro + 512]);                                \
        GN[i2] = __bfloat162float(gxs[ro + 1024]);                               \
      }                                                                          \
      asm volatile("" ::: "memory");                                             \
      /* speculative DMA of hidden[s]: consumed after the sister phase */        \
      const bf16* dsrc = hidden + ((long)s*64 + (B0))*512 + lane*8;              \
      _Pragma("unroll")                                                          \
      for (int b = 0; b < 8; ++b) GL2LDS(dsrc + b*512, &HP[b*KP]);               \
      asm volatile("" ::: "memory");                                             \
    }                                                                            \
  }

__global__ __launch_bounds__(64, 1) void k_gru(
    const bf16* __restrict__ gx,   // [s][b][1536] bf16 (bih already added)
    const bf16* __restrict__ Whh,  // [1536][512] bf16
    const float* __restrict__ bhh, // [1536]
    bf16* __restrict__ hidden)     // [s][b][512] bf16, pre-memset 0xFF
{
  const int lane = threadIdx.x & 63;
  const int c16  = lane & 15, quad = lane >> 4;
  const int pw   = blockIdx.x & 31;     // column producer id (cols 16pw..16pw+16)
  const int pr   = blockIdx.x >> 5;     // pair id 0..3
  const int hwv  = pw * 16;
  const int bA   = pr * 16;             // group A batches [bA, bA+8)
  const int bB   = pr * 16 + 8;         // group B batches [bB, bB+8)

  __shared__ bf16 wlds[16 * 3 * 64 * 8];  // [kt][gate][lane*8] : 49,152 B (shared A/B)
  __shared__ bf16 hpA[8 * KP];            // group A h_prev: 8,320 B
  __shared__ bf16 hpB[8 * KP];            // group B h_prev: 8,320 B

  // one-time stage: B-frag for (kt,gate) at this lane, lane-contiguous (conflict-free)
  for (int g3 = 0; g3 < 3; ++g3)
    for (int kt = 0; kt < 16; ++kt)
      *(short8*)&wlds[((kt*3 + g3)*64 + lane)*8] =
          *(const short8*)&Whh[(long)(g3*512 + hwv + c16)*512 + kt*32 + quad*8];
  const float bhr = bhh[       hwv + c16];
  const float bhz = bhh[ 512 + hwv + c16];
  const float bhn = bhh[1024 + hwv + c16];
  __syncthreads();

  // sentinel vector (0xFFFFFFFF dwords -- never produced by the GRU since |h|<1)
  union SU { unsigned u[4]; short8 s8; } su_;
  su_.u[0] = su_.u[1] = su_.u[2] = su_.u[3] = 0xFFFFFFFFu;
  const short8 sentv = su_.s8;

  // lane owns output batch rows brv..brv+3 (valid for quad<2; quads 2,3 mirror)
  const int brv = (quad & 1) * 4;

  float grA[4], gzA[4], gnA[4], grB[4], gzB[4], gnB[4];
  float hcA[4] = {0.f,0.f,0.f,0.f}, hcB[4] = {0.f,0.f,0.f,0.f};
  { // gx for s=0, both groups
    const bf16* ga = gx + (long)bA * 1536 + hwv + c16;
    const bf16* gb = gx + (long)bB * 1536 + hwv + c16;
#pragma unroll
    for (int i2 = 0; i2 < 4; ++i2) {
      const long ro = (long)(brv + i2) * 1536;
      grA[i2] = __bfloat162float(ga[ro]);
      gzA[i2] = __bfloat162float(ga[ro + 512]);
      gnA[i2] = __bfloat162float(ga[ro + 1024]);
      grB[i2] = __bfloat162float(gb[ro]);
      gzB[i2] = __bfloat162float(gb[ro + 512]);
      gnB[i2] = __bfloat162float(gb[ro + 1024]);
    }
  }

  for (int s = 0; s < 510; ++s) {
    GRU_PHASE(hpA, bA, grA, gzA, gnA, hcA);   // phase A (waits A-DMA from prev iter)
    GRU_PHASE(hpB, bB, grB, gzB, gnB, hcB);   // phase B (A-DMA flies under this)
  }
}

// ---------------- launch ----------------
extern "C" void kernel_launch(void* const* d_in, const int* in_sizes, int n_in,
                              void* d_out, int out_size, void* d_ws, size_t ws_size,
                              hipStream_t stream)
{
  const float* x    = (const float*)d_in[0];
  const int*   sidx = (const int*)d_in[1];
  const float* sW   = (const float*)d_in[2];
  const float* sb   = (const float*)d_in[3];
  const float* pW   = (const float*)d_in[4];
  const float* pb   = (const float*)d_in[5];
  const float* rsc  = (const float*)d_in[6];
  const float* wih  = (const float*)d_in[7];
  const float* whh  = (const float*)d_in[8];
  const float* bih  = (const float*)d_in[9];
  const float* bhh  = (const float*)d_in[10];
  const float* w1   = (const float*)d_in[11];
  const float* b1   = (const float*)d_in[12];
  const float* w2   = (const float*)d_in[13];
  const float* b2   = (const float*)d_in[14];
  char* ws = (char*)d_ws;
  float* out = (float*)d_out;

  bf16* xbf   = (bf16*)(ws + O_XBF);
  bf16* swbf  = (bf16*)(ws + O_SWB);
  bf16* pwbf  = (bf16*)(ws + O_PW);
  bf16* wihbf = (bf16*)(ws + O_WIH);
  bf16* whhbf = (bf16*)(ws + O_WHH);
  bf16* w1bf  = (bf16*)(ws + O_W1);
  bf16* w2bf  = (bf16*)(ws + O_W2);
  bf16* tokbf = (bf16*)(ws + O_TOK);
  bf16* hbf   = (bf16*)(ws + O_HBF);
  bf16* hidbf = (bf16*)(ws + O_HID);
  bf16* abf   = (bf16*)(ws + O_ABF);
  float* hpre = (float*)(ws + O_GX);  // fp32 h_pre overlaps gx region
  bf16* gxbf  = (bf16*)(ws + O_GX);

  // sentinel-fill hidden: 0xFF dwords are never produced by the GRU (|h|<1)
  hipMemsetAsync(ws + O_HID, 0xFF, HID_BYTES, stream);

  auto cvt = [&](const float* s, bf16* dp, long n) {
    int n4 = (int)(n >> 2);
    k_f2b<<<dim3((n4 + 255) / 256), dim3(256), 0, stream>>>(s, dp, n4);
  };
  cvt(x,   xbf,   (long)B_*T_*D_);
  cvt(sW,  swbf,  16L*128*128);
  cvt(pW,  pwbf,  512L*384);
  cvt(wih, wihbf, 1536L*512);
  cvt(whh, whhbf, 1536L*512);
  cvt(w1,  w1bf,  3L*512*512);
  cvt(w2,  w2bf,  3L*384*512);

  // 1) session align -> tokens (fp32 to d_out [b][n][tok], bf16 to ws rows [n*64+b])
  k_gemm<EPI_TOK><<<dim3(4, 1, 64), dim3(256), 0, stream>>>(
      xbf, swbf, sb, nullptr, 128, 0,
      (long)T_*D_, 128L*128, 128L, 0L, sidx, out + TOKOFF_, tokbf);

  // 2) proj: h_pre = tokens @ proj_W^T + b  (fp32, rows [n*64+b])
  k_gemm<EPI_F32><<<dim3(255, 4, 1), dim3(256), 0, stream>>>(
      tokbf, pwbf, pb, hpre, 384, 512, 0, 0, 0, 0, nullptr, nullptr, nullptr);

  // 3) RMSNorm -> h bf16
  k_rms<<<dim3(8160), dim3(256), 0, stream>>>(hpre, rsc, hbf);

  // 4) gx = h @ Wih^T + bih  (bf16, rows [n*64+b] == [s][b][1536])
  k_gemm<EPI_BF16><<<dim3(255, 12, 1), dim3(256), 0, stream>>>(
      hbf, wihbf, bih, gxbf, 512, 1536, 0, 0, 0, 0, nullptr, nullptr, nullptr);

  // 5) GRU scan: 4 pairs x 32 col-producers = 128 WGs x 64 thr; each wave
  //    serves two independent batch groups in interleaved, software-pipelined
  //    phases. Flagless sentinel protocol (r7-proven, sc1 both sides).
  k_gru<<<dim3(128), dim3(64), 0, stream>>>(gxbf, whhbf, bhh, hidbf);

  // 6) heads: a = gelu(hidden @ W1^T + b1); preds = a @ W2^T + b2 (remap rows)
  for (int k = 0; k < 3; ++k) {
    k_gemm<EPI_GELU><<<dim3(255, 4, 1), dim3(256), 0, stream>>>(
        hidbf, w1bf + (long)k*512*512, b1 + (long)k*512, abf,
        512, 512, 0, 0, 0, 0, nullptr, nullptr, nullptr);
    k_gemm<EPI_F32R><<<dim3(255, 3, 1), dim3(256), 0, stream>>>(
        abf, w2bf + (long)k*384*512, b2 + (long)k*384, out + (long)k*PRED1_,
        512, 384, 0, 0, 0, 0, nullptr, nullptr, nullptr);
  }
}

// Round 10
// 2474.531 us; speedup vs baseline: 1.4576x; 1.4576x over previous
//
#include <hip/hip_runtime.h>
#include <hip/hip_bf16.h>
#include <math.h>

typedef __hip_bfloat16 bf16;
typedef __attribute__((ext_vector_type(8))) short short8;
typedef __attribute__((ext_vector_type(4))) short short4v;
typedef __attribute__((ext_vector_type(4))) float f32x4;

// problem dims
#define B_    64
#define T_    512
#define D_    128
#define N_    510
#define H_    512
#define TOK_  384
#define PRED1_ 12533760L  // B_*N_*TOK_
#define TOKOFF_ 37601280L // 3*PRED1_ : tokens offset in d_out (floats)

// ---- workspace layout (bytes) ----
#define O_XBF  0UL            // x bf16            8,388,608
#define O_SWB  8388608UL      // sess_W bf16         524,288
#define O_PW   8912896UL      // proj_W bf16         393,216
#define O_WIH  9306112UL      // gru_Wih bf16      1,572,864
#define O_WHH  10878976UL     // gru_Whh bf16      1,572,864
#define O_W1   12451840UL     // head_W1 bf16      1,572,864
#define O_W2   14024704UL     // head_W2 bf16      1,179,648
#define O_TOK  15204352UL     // tokens bf16      25,067,520  rows [n*64+b]
#define O_HBF  40271872UL     // h bf16 (post-RMS)33,423,360
#define O_HID  73695232UL     // hidden bf16      33,423,360  rows [s*64+b]
#define O_ABF  107118592UL    // gelu act bf16
#define O_GX   140541952UL    // gx bf16 100,270,080 (h_pre fp32 overlapped first)

#define HID_BYTES 33423360UL

// ---------------- fp32 -> bf16 convert ----------------
__global__ void k_f2b(const float* __restrict__ s, bf16* __restrict__ d, int n4) {
  int i = blockIdx.x * 256 + threadIdx.x;
  if (i < n4) {
    float4 v = ((const float4*)s)[i];
    union { short4v sv; bf16 h[4]; } u;
    u.h[0] = __float2bfloat16(v.x); u.h[1] = __float2bfloat16(v.y);
    u.h[2] = __float2bfloat16(v.z); u.h[3] = __float2bfloat16(v.w);
    ((short4v*)d)[i] = u.sv;
  }
}

// ---------------- generic bf16 MFMA GEMM: C = A[M,K] @ W[N,K]^T + bias ----------------
enum { EPI_F32 = 0, EPI_BF16 = 1, EPI_GELU = 2, EPI_TOK = 3, EPI_F32R = 4 };
#define SLDA 40

template <int EPI>
__global__ __launch_bounds__(256, 2) void k_gemm(
    const bf16* __restrict__ A, const bf16* __restrict__ W,
    const float* __restrict__ bias, void* __restrict__ C,
    int K, int ldc, long zA, long zW, long zB, long zC,
    const int* __restrict__ sidx, float* __restrict__ tokf, bf16* __restrict__ tokb)
{
  const int tid = threadIdx.x;
  const int bm = blockIdx.x, bn = blockIdx.y, z = blockIdx.z;
  const int wsel = (EPI == EPI_TOK) ? sidx[z] : z;
  const int lane = tid & 63, wave = tid >> 6;
  const int wm = (wave & 1) << 6, wn = (wave >> 1) << 6;
  const int r16 = lane & 15, quad = lane >> 4;

  __shared__ bf16 sA[128 * SLDA];
  __shared__ bf16 sB[128 * SLDA];

  const bf16* Ag = A + (long)z * zA + (long)bm * 128 * K;
  const bf16* Wg = W + (long)wsel * zW + (long)bn * 128 * K;

  f32x4 zf = {0.f, 0.f, 0.f, 0.f};
  f32x4 acc[4][4];
  for (int i = 0; i < 4; ++i) for (int j = 0; j < 4; ++j) acc[i][j] = zf;

  const int sr = tid >> 1, sc = (tid & 1) << 4;
  for (int k0 = 0; k0 < K; k0 += 32) {
    *(short8*)&sA[sr*SLDA + sc]     = *(const short8*)&Ag[(long)sr*K + k0 + sc];
    *(short8*)&sA[sr*SLDA + sc + 8] = *(const short8*)&Ag[(long)sr*K + k0 + sc + 8];
    *(short8*)&sB[sr*SLDA + sc]     = *(const short8*)&Wg[(long)sr*K + k0 + sc];
    *(short8*)&sB[sr*SLDA + sc + 8] = *(const short8*)&Wg[(long)sr*K + k0 + sc + 8];
    __syncthreads();
    short8 fa[4], fb[4];
    for (int i = 0; i < 4; ++i) fa[i] = *(const short8*)&sA[(wm + i*16 + r16)*SLDA + quad*8];
    for (int j = 0; j < 4; ++j) fb[j] = *(const short8*)&sB[(wn + j*16 + r16)*SLDA + quad*8];
    for (int i = 0; i < 4; ++i)
      for (int j = 0; j < 4; ++j)
        acc[i][j] = __builtin_amdgcn_mfma_f32_16x16x32_bf16(fa[i], fb[j], acc[i][j], 0, 0, 0);
    __syncthreads();
  }

  const float* bz = bias + (long)wsel * zB + bn * 128;
  for (int i = 0; i < 4; ++i) {
    for (int j = 0; j < 4; ++j) {
      const int colL = wn + j*16 + r16;
      const float bv = bz[colL];
      for (int r = 0; r < 4; ++r) {
        float v = acc[i][j][r] + bv;
        const long grow = (long)bm*128 + wm + i*16 + quad*4 + r;
        const long gcol = (long)bn*128 + colL;
        if (EPI == EPI_F32) {
          ((float*)C)[(long)z*zC + grow*ldc + gcol] = v;
        } else if (EPI == EPI_BF16) {
          ((bf16*)C)[(long)z*zC + grow*ldc + gcol] = __float2bfloat16(v);
        } else if (EPI == EPI_GELU) {
          v = 0.5f * v * (1.0f + erff(v * 0.70710678118654752f));
          ((bf16*)C)[(long)z*zC + grow*ldc + gcol] = __float2bfloat16(v);
        } else if (EPI == EPI_F32R) {
          // rows are [n*64+b]; output wants [b*510+n]
          const long rb = grow & 63, rn = grow >> 6;
          ((float*)C)[(rb*510 + rn)*ldc + gcol] = v;
        } else { // EPI_TOK: z=batch, grow=t, gcol=e
          for (int p = 0; p < 3; ++p) {
            long n = grow - p;
            if (n >= 0 && n < N_) {
              tokf[((long)z*N_ + n)*TOK_ + gcol*3 + p] = v;                 // d_out: [b][n][tok]
              tokb[((long)n*B_ + z)*TOK_ + gcol*3 + p] = __float2bfloat16(v); // ws: rows [n*64+b]
            }
          }
        }
      }
    }
  }
}

// ---------------- RMSNorm rows of 512: fp32 in -> bf16 out ----------------
__global__ __launch_bounds__(256) void k_rms(const float* __restrict__ hpre,
                                             const float* __restrict__ scale,
                                             bf16* __restrict__ hbf)
{
  const int wave = threadIdx.x >> 6, lane = threadIdx.x & 63;
  const long row = (long)blockIdx.x * 4 + wave;
  const float* p = hpre + row * 512 + lane * 8;
  float4 v0 = *(const float4*)p;
  float4 v1 = *(const float4*)(p + 4);
  float ss = v0.x*v0.x + v0.y*v0.y + v0.z*v0.z + v0.w*v0.w
           + v1.x*v1.x + v1.y*v1.y + v1.z*v1.z + v1.w*v1.w;
  for (int m = 32; m >= 1; m >>= 1) ss += __shfl_xor(ss, m, 64);
  const float inv = 1.0f / sqrtf(ss * (1.0f/512.0f) + 1e-6f);
  const float* sc = scale + lane * 8;
  union { short8 sv; bf16 h[8]; } u;
  u.h[0] = __float2bfloat16(v0.x*inv*sc[0]); u.h[1] = __float2bfloat16(v0.y*inv*sc[1]);
  u.h[2] = __float2bfloat16(v0.z*inv*sc[2]); u.h[3] = __float2bfloat16(v0.w*inv*sc[3]);
  u.h[4] = __float2bfloat16(v1.x*inv*sc[4]); u.h[5] = __float2bfloat16(v1.y*inv*sc[5]);
  u.h[6] = __float2bfloat16(v1.z*inv*sc[6]); u.h[7] = __float2bfloat16(v1.w*inv*sc[7]);
  *(short8*)(hbf + row * 512 + lane * 8) = u.sv;
}

// ---------------- GRU: 3-wave gate-split + flagless sentinel scan ----------------
// Fuses the two proven 3.0us/step structures:
//  r7 protocol (kept exactly): hidden pre-memset 0xFF; |h|<1 so stored dwords
//    never 0xFFFFFFFF; wave0 speculatively DMAs h[s-1] and validates via its
//    A-frag reads; retry re-DMAs. No flags, no acks, sc1 both sides.
//  r2 structure: WG = 192 thr / 3 waves; wave g computes gate g for the same
//    16 columns -> the 48 MFMAs + 64 ds_reads + 12 gx loads that r7 serialized
//    on one wave now issue concurrently on 3 SIMDs.
// Barriers are UNCONDITIONAL each iteration (no conditional-barrier hangs);
// lgkmcnt(0) precedes barrier2 so next iter's DMA can't race hp reads.
#define KP 520   // LDS row pad (elems)

// aux=16 == CPol SC1 on gfx950: device-scope load (coherent past L2) -- r7-proven
#define GL2LDS(g, l) __builtin_amdgcn_global_load_lds( \
    (const __attribute__((address_space(1))) void*)(g), \
    (__attribute__((address_space(3))) void*)(l), 16, 0, 16)

__global__ __launch_bounds__(192, 1) void k_gru(
    const bf16* __restrict__ gx,   // [s][b][1536] bf16 (bih already added)
    const bf16* __restrict__ Whh,  // [1536][512] bf16
    const float* __restrict__ bhh, // [1536]
    bf16* __restrict__ hidden)     // [s][b][512] bf16, pre-memset 0xFF
{
  const int tid  = threadIdx.x;
  const int wv   = tid / 64;            // gate: 0=r 1=z 2=n
  const int lane = tid & 63;
  const int c16  = lane & 15, quad = lane >> 4;
  const int pw   = blockIdx.x & 31;     // column producer id
  const int gb   = blockIdx.x >> 5;     // batch group
  const int hwv  = pw * 16;             // column base
  const int b0   = gb * 8;              // batch base

  __shared__ bf16 wlds[16 * 3 * 64 * 8];  // [kt][gate][lane*8] : 49,152 B
  __shared__ bf16 hp[8 * KP];             // h_prev rows (DMA dest): 8,320 B
  __shared__ float ex[2][8 * 16];         // r,z sigmoids: 1,024 B

  // one-time stage: wave g stages its own gate's B-frags, lane-contiguous
  for (int kt = 0; kt < 16; ++kt)
    *(short8*)&wlds[((kt*3 + wv)*64 + lane)*8] =
        *(const short8*)&Whh[(long)(wv*512 + hwv + c16)*512 + kt*32 + quad*8];
  const float bh = bhh[wv*512 + hwv + c16];
  __syncthreads();

  // lane owns output batch rows brv..brv+3 (valid for quad<2; quads 2,3 mirror)
  const int brv = (quad & 1) * 4;

  float gv[4];                            // this wave's gate gx values
  float hcur[4] = {0.f, 0.f, 0.f, 0.f};   // wave2 only: own cols' h, in regs
  { // gx for s=0 (each wave loads only its gate: 4 loads)
    const bf16* gxs = gx + (long)b0 * 1536 + wv*512 + hwv + c16;
#pragma unroll
    for (int i2 = 0; i2 < 4; ++i2)
      gv[i2] = __bfloat162float(gxs[(long)(brv + i2) * 1536]);
  }

  for (int s = 0; s < 510; ++s) {
    f32x4 acc = {0.f, 0.f, 0.f, 0.f};
    union AU { unsigned u[4]; short8 s8; } au[16];

    if (s > 0 && wv == 0) {
      // r7 detect loop: speculative DMA + validate via A-frag reads
      const bf16* src = hidden + ((long)(s-1)*64 + b0)*512 + lane*8;
      while (true) {
#pragma unroll
        for (int b = 0; b < 8; ++b) GL2LDS(src + b*512, &hp[b*KP]);
        asm volatile("s_waitcnt vmcnt(0)" ::: "memory");
        unsigned mx = 0u;
#pragma unroll
        for (int kt = 0; kt < 16; ++kt) {
          au[kt].s8 = *(const short8*)&hp[(c16 & 7)*KP + kt*32 + quad*8];
          unsigned m01 = au[kt].u[0] > au[kt].u[1] ? au[kt].u[0] : au[kt].u[1];
          unsigned m23 = au[kt].u[2] > au[kt].u[3] ? au[kt].u[2] : au[kt].u[3];
          unsigned m = m01 > m23 ? m01 : m23;
          mx = mx > m ? mx : m;
        }
        if (__all(mx != 0xFFFFFFFFu)) break;
      }
    }
    __syncthreads();   // barrier1: hp valid for all waves

    if (s > 0) {
      if (wv != 0) {   // waves 1,2 read A-frags now (wave0 already has them)
#pragma unroll
        for (int kt = 0; kt < 16; ++kt)
          au[kt].s8 = *(const short8*)&hp[(c16 & 7)*KP + kt*32 + quad*8];
      }
      // 16 MFMAs per wave, 3 waves concurrent on different SIMDs
#pragma unroll
      for (int kt = 0; kt < 16; ++kt) {
        short8 fb = *(const short8*)&wlds[((kt*3 + wv)*64 + lane)*8];
        acc = __builtin_amdgcn_mfma_f32_16x16x32_bf16(au[kt].s8, fb, acc, 0, 0, 0);
      }
    }

    if (wv < 2) {  // r and z: sigmoid, publish to ex
      if (quad < 2) {
#pragma unroll
        for (int i2 = 0; i2 < 4; ++i2)
          ex[wv][(quad*4 + i2)*16 + c16] =
              1.0f / (1.0f + expf(-(gv[i2] + acc[i2] + bh)));
      }
    }
    asm volatile("s_waitcnt lgkmcnt(0)" ::: "memory");  // hp/ex traffic drained
    __syncthreads();   // barrier2: ex ready; hp reads complete (DMA may overwrite)

    if (wv == 2 && quad < 2) {  // n-wave finishes the step and publishes
#pragma unroll
      for (int i2 = 0; i2 < 4; ++i2) {
        const int br = brv + i2;
        const float rr = ex[0][br*16 + c16];
        const float zz = ex[1][br*16 + c16];
        const float nn = tanhf(gv[i2] + rr * (acc[i2] + bh));
        const float hn = (1.0f - zz)*nn + zz*hcur[i2];
        union { bf16 h; unsigned short u; } cb; cb.h = __float2bfloat16(hn);
        hcur[i2] = __bfloat162float(cb.h);     // exact stored value for next step
        unsigned mine = cb.u;
        unsigned part = (unsigned)__shfl_xor((int)mine, 1, 64);
        if (!(c16 & 1)) {
          unsigned w = (part << 16) | mine;    // lo = col c16, hi = col c16+1
          __hip_atomic_store((unsigned*)(hidden + ((long)s*64 + b0 + br)*512 + hwv + c16),
                             w, __ATOMIC_RELAXED, __HIP_MEMORY_SCOPE_AGENT);
        }
      }
    }
    if (s < 509) {
      asm volatile("" ::: "memory");  // keep gx prefetch BELOW the stores
      // prefetch own gate's gx for s+1 (4 loads; hides under next detect)
      const bf16* gxs = gx + ((long)(s+1)*64 + b0)*1536 + wv*512 + hwv + c16;
#pragma unroll
      for (int i2 = 0; i2 < 4; ++i2)
        gv[i2] = __bfloat162float(gxs[(long)(brv + i2) * 1536]);
    }
  }
}

// ---------------- launch ----------------
extern "C" void kernel_launch(void* const* d_in, const int* in_sizes, int n_in,
                              void* d_out, int out_size, void* d_ws, size_t ws_size,
                              hipStream_t stream)
{
  const float* x    = (const float*)d_in[0];
  const int*   sidx = (const int*)d_in[1];
  const float* sW   = (const float*)d_in[2];
  const float* sb   = (const float*)d_in[3];
  const float* pW   = (const float*)d_in[4];
  const float* pb   = (const float*)d_in[5];
  const float* rsc  = (const float*)d_in[6];
  const float* wih  = (const float*)d_in[7];
  const float* whh  = (const float*)d_in[8];
  const float* bih  = (const float*)d_in[9];
  const float* bhh  = (const float*)d_in[10];
  const float* w1   = (const float*)d_in[11];
  const float* b1   = (const float*)d_in[12];
  const float* w2   = (const float*)d_in[13];
  const float* b2   = (const float*)d_in[14];
  char* ws = (char*)d_ws;
  float* out = (float*)d_out;

  bf16* xbf   = (bf16*)(ws + O_XBF);
  bf16* swbf  = (bf16*)(ws + O_SWB);
  bf16* pwbf  = (bf16*)(ws + O_PW);
  bf16* wihbf = (bf16*)(ws + O_WIH);
  bf16* whhbf = (bf16*)(ws + O_WHH);
  bf16* w1bf  = (bf16*)(ws + O_W1);
  bf16* w2bf  = (bf16*)(ws + O_W2);
  bf16* tokbf = (bf16*)(ws + O_TOK);
  bf16* hbf   = (bf16*)(ws + O_HBF);
  bf16* hidbf = (bf16*)(ws + O_HID);
  bf16* abf   = (bf16*)(ws + O_ABF);
  float* hpre = (float*)(ws + O_GX);  // fp32 h_pre overlaps gx region
  bf16* gxbf  = (bf16*)(ws + O_GX);

  // sentinel-fill hidden: 0xFF dwords are never produced by the GRU (|h|<1)
  hipMemsetAsync(ws + O_HID, 0xFF, HID_BYTES, stream);

  auto cvt = [&](const float* s, bf16* dp, long n) {
    int n4 = (int)(n >> 2);
    k_f2b<<<dim3((n4 + 255) / 256), dim3(256), 0, stream>>>(s, dp, n4);
  };
  cvt(x,   xbf,   (long)B_*T_*D_);
  cvt(sW,  swbf,  16L*128*128);
  cvt(pW,  pwbf,  512L*384);
  cvt(wih, wihbf, 1536L*512);
  cvt(whh, whhbf, 1536L*512);
  cvt(w1,  w1bf,  3L*512*512);
  cvt(w2,  w2bf,  3L*384*512);

  // 1) session align -> tokens (fp32 to d_out [b][n][tok], bf16 to ws rows [n*64+b])
  k_gemm<EPI_TOK><<<dim3(4, 1, 64), dim3(256), 0, stream>>>(
      xbf, swbf, sb, nullptr, 128, 0,
      (long)T_*D_, 128L*128, 128L, 0L, sidx, out + TOKOFF_, tokbf);

  // 2) proj: h_pre = tokens @ proj_W^T + b  (fp32, rows [n*64+b])
  k_gemm<EPI_F32><<<dim3(255, 4, 1), dim3(256), 0, stream>>>(
      tokbf, pwbf, pb, hpre, 384, 512, 0, 0, 0, 0, nullptr, nullptr, nullptr);

  // 3) RMSNorm -> h bf16
  k_rms<<<dim3(8160), dim3(256), 0, stream>>>(hpre, rsc, hbf);

  // 4) gx = h @ Wih^T + bih  (bf16, rows [n*64+b] == [s][b][1536])
  k_gemm<EPI_BF16><<<dim3(255, 12, 1), dim3(256), 0, stream>>>(
      hbf, wihbf, bih, gxbf, 512, 1536, 0, 0, 0, 0, nullptr, nullptr, nullptr);

  // 5) GRU scan: 8 groups x 32 col-producers = 256 WGs x 192 thr (3 waves).
  //    Flagless sentinel protocol; gate-split compute across the 3 waves.
  k_gru<<<dim3(256), dim3(192), 0, stream>>>(gxbf, whhbf, bhh, hidbf);

  // 6) heads: a = gelu(hidden @ W1^T + b1); preds = a @ W2^T + b2 (remap rows)
  for (int k = 0; k < 3; ++k) {
    k_gemm<EPI_GELU><<<dim3(255, 4, 1), dim3(256), 0, stream>>>(
        hidbf, w1bf + (long)k*512*512, b1 + (long)k*512, abf,
        512, 512, 0, 0, 0, 0, nullptr, nullptr, nullptr);
    k_gemm<EPI_F32R><<<dim3(255, 3, 1), dim3(256), 0, stream>>>(
        abf, w2bf + (long)k*384*512, b2 + (long)k*384, out + (long)k*PRED1_,
        512, 384, 0, 0, 0, 0, nullptr, nullptr, nullptr);
  }
}

// Round 11
// 2290.617 us; speedup vs baseline: 1.5746x; 1.0803x over previous
//
#include <hip/hip_runtime.h>
#include <hip/hip_bf16.h>
#include <math.h>

typedef __hip_bfloat16 bf16;
typedef __attribute__((ext_vector_type(8))) short short8;
typedef __attribute__((ext_vector_type(4))) short short4v;
typedef __attribute__((ext_vector_type(4))) float f32x4;

// problem dims
#define B_    64
#define T_    512
#define D_    128
#define N_    510
#define H_    512
#define TOK_  384
#define PRED1_ 12533760L  // B_*N_*TOK_
#define TOKOFF_ 37601280L // 3*PRED1_ : tokens offset in d_out (floats)

// ---- workspace layout (bytes) ----
#define O_XBF  0UL            // x bf16            8,388,608
#define O_SWB  8388608UL      // sess_W bf16         524,288
#define O_PW   8912896UL      // proj_W bf16         393,216
#define O_WIH  9306112UL      // gru_Wih bf16      1,572,864
#define O_WHH  10878976UL     // gru_Whh bf16      1,572,864
#define O_W1   12451840UL     // head_W1 bf16      1,572,864
#define O_W2   14024704UL     // head_W2 bf16      1,179,648
#define O_TOK  15204352UL     // tokens bf16      25,067,520  rows [n*64+b]
#define O_HBF  40271872UL     // h bf16 (post-RMS)33,423,360
#define O_HID  73695232UL     // hidden bf16      33,423,360  rows [s*64+b]
#define O_ABF  107118592UL    // gelu act bf16
#define O_GX   140541952UL    // gx bf16 100,270,080 (h_pre fp32 overlapped first)

#define HID_BYTES 33423360UL

// ---------------- fp32 -> bf16 convert ----------------
__global__ void k_f2b(const float* __restrict__ s, bf16* __restrict__ d, int n4) {
  int i = blockIdx.x * 256 + threadIdx.x;
  if (i < n4) {
    float4 v = ((const float4*)s)[i];
    union { short4v sv; bf16 h[4]; } u;
    u.h[0] = __float2bfloat16(v.x); u.h[1] = __float2bfloat16(v.y);
    u.h[2] = __float2bfloat16(v.z); u.h[3] = __float2bfloat16(v.w);
    ((short4v*)d)[i] = u.sv;
  }
}

// ---------------- generic bf16 MFMA GEMM: C = A[M,K] @ W[N,K]^T + bias ----------------
enum { EPI_F32 = 0, EPI_BF16 = 1, EPI_GELU = 2, EPI_TOK = 3, EPI_F32R = 4 };
#define SLDA 40

template <int EPI>
__global__ __launch_bounds__(256, 2) void k_gemm(
    const bf16* __restrict__ A, const bf16* __restrict__ W,
    const float* __restrict__ bias, void* __restrict__ C,
    int K, int ldc, long zA, long zW, long zB, long zC,
    const int* __restrict__ sidx, float* __restrict__ tokf, bf16* __restrict__ tokb)
{
  const int tid = threadIdx.x;
  const int bm = blockIdx.x, bn = blockIdx.y, z = blockIdx.z;
  const int wsel = (EPI == EPI_TOK) ? sidx[z] : z;
  const int lane = tid & 63, wave = tid >> 6;
  const int wm = (wave & 1) << 6, wn = (wave >> 1) << 6;
  const int r16 = lane & 15, quad = lane >> 4;

  __shared__ bf16 sA[128 * SLDA];
  __shared__ bf16 sB[128 * SLDA];

  const bf16* Ag = A + (long)z * zA + (long)bm * 128 * K;
  const bf16* Wg = W + (long)wsel * zW + (long)bn * 128 * K;

  f32x4 zf = {0.f, 0.f, 0.f, 0.f};
  f32x4 acc[4][4];
  for (int i = 0; i < 4; ++i) for (int j = 0; j < 4; ++j) acc[i][j] = zf;

  const int sr = tid >> 1, sc = (tid & 1) << 4;
  for (int k0 = 0; k0 < K; k0 += 32) {
    *(short8*)&sA[sr*SLDA + sc]     = *(const short8*)&Ag[(long)sr*K + k0 + sc];
    *(short8*)&sA[sr*SLDA + sc + 8] = *(const short8*)&Ag[(long)sr*K + k0 + sc + 8];
    *(short8*)&sB[sr*SLDA + sc]     = *(const short8*)&Wg[(long)sr*K + k0 + sc];
    *(short8*)&sB[sr*SLDA + sc + 8] = *(const short8*)&Wg[(long)sr*K + k0 + sc + 8];
    __syncthreads();
    short8 fa[4], fb[4];
    for (int i = 0; i < 4; ++i) fa[i] = *(const short8*)&sA[(wm + i*16 + r16)*SLDA + quad*8];
    for (int j = 0; j < 4; ++j) fb[j] = *(const short8*)&sB[(wn + j*16 + r16)*SLDA + quad*8];
    for (int i = 0; i < 4; ++i)
      for (int j = 0; j < 4; ++j)
        acc[i][j] = __builtin_amdgcn_mfma_f32_16x16x32_bf16(fa[i], fb[j], acc[i][j], 0, 0, 0);
    __syncthreads();
  }

  const float* bz = bias + (long)wsel * zB + bn * 128;
  for (int i = 0; i < 4; ++i) {
    for (int j = 0; j < 4; ++j) {
      const int colL = wn + j*16 + r16;
      const float bv = bz[colL];
      for (int r = 0; r < 4; ++r) {
        float v = acc[i][j][r] + bv;
        const long grow = (long)bm*128 + wm + i*16 + quad*4 + r;
        const long gcol = (long)bn*128 + colL;
        if (EPI == EPI_F32) {
          ((float*)C)[(long)z*zC + grow*ldc + gcol] = v;
        } else if (EPI == EPI_BF16) {
          ((bf16*)C)[(long)z*zC + grow*ldc + gcol] = __float2bfloat16(v);
        } else if (EPI == EPI_GELU) {
          v = 0.5f * v * (1.0f + erff(v * 0.70710678118654752f));
          ((bf16*)C)[(long)z*zC + grow*ldc + gcol] = __float2bfloat16(v);
        } else if (EPI == EPI_F32R) {
          // rows are [n*64+b]; output wants [b*510+n]
          const long rb = grow & 63, rn = grow >> 6;
          ((float*)C)[(rb*510 + rn)*ldc + gcol] = v;
        } else { // EPI_TOK: z=batch, grow=t, gcol=e
          for (int p = 0; p < 3; ++p) {
            long n = grow - p;
            if (n >= 0 && n < N_) {
              tokf[((long)z*N_ + n)*TOK_ + gcol*3 + p] = v;                 // d_out: [b][n][tok]
              tokb[((long)n*B_ + z)*TOK_ + gcol*3 + p] = __float2bfloat16(v); // ws: rows [n*64+b]
            }
          }
        }
      }
    }
  }
}

// ---------------- RMSNorm rows of 512: fp32 in -> bf16 out ----------------
__global__ __launch_bounds__(256) void k_rms(const float* __restrict__ hpre,
                                             const float* __restrict__ scale,
                                             bf16* __restrict__ hbf)
{
  const int wave = threadIdx.x >> 6, lane = threadIdx.x & 63;
  const long row = (long)blockIdx.x * 4 + wave;
  const float* p = hpre + row * 512 + lane * 8;
  float4 v0 = *(const float4*)p;
  float4 v1 = *(const float4*)(p + 4);
  float ss = v0.x*v0.x + v0.y*v0.y + v0.z*v0.z + v0.w*v0.w
           + v1.x*v1.x + v1.y*v1.y + v1.z*v1.z + v1.w*v1.w;
  for (int m = 32; m >= 1; m >>= 1) ss += __shfl_xor(ss, m, 64);
  const float inv = 1.0f / sqrtf(ss * (1.0f/512.0f) + 1e-6f);
  const float* sc = scale + lane * 8;
  union { short8 sv; bf16 h[8]; } u;
  u.h[0] = __float2bfloat16(v0.x*inv*sc[0]); u.h[1] = __float2bfloat16(v0.y*inv*sc[1]);
  u.h[2] = __float2bfloat16(v0.z*inv*sc[2]); u.h[3] = __float2bfloat16(v0.w*inv*sc[3]);
  u.h[4] = __float2bfloat16(v1.x*inv*sc[4]); u.h[5] = __float2bfloat16(v1.y*inv*sc[5]);
  u.h[6] = __float2bfloat16(v1.z*inv*sc[6]); u.h[7] = __float2bfloat16(v1.w*inv*sc[7]);
  *(short8*)(hbf + row * 512 + lane * 8) = u.sv;
}

// ---------------- GRU: flagless sentinel scan, probe-then-fetch detect ----------------
// r7 structure kept exactly (champion: 1530us): 8 groups x 32 single-wave WGs,
// 256 WGs x 64 thr (1 wave/CU); wave owns 16 cols, all 3 gates; weights in LDS
// [kt][gate][lane*8] (conflict-free); hcur in regs; sentinel protocol (hidden
// pre-memset 0xFF, |h|<1 so stored dwords never 0xFFFFFFFF; no flags, no acks).
// NEW (r11): the detect loop is split into PROBE + FETCH. r7's loop was both
// detector and payload (8KB DMA + 16 ds_read validate = ~1100cy + 8KB of L3
// traffic PER POLL; 256 concurrent pollers -> multi-TB/s L3 burst pressure).
// Probe re-DMAs only row 0 (1KB) and validates it with ONE b128/lane (row 0
// holds a dword from every producer -> row-0-valid <=> all 32 producers have
// begun publishing). Only then run the full 8KB fetch + full validate (still
// authoritative: no assumption about a producer's row-0 vs rows-1..7 order).
// ~8x less retry traffic + ~1.6x finer detect granularity.
#define KP 520   // LDS row pad (elems)

// aux=16 == CPol SC1 on gfx950: device-scope load (coherent past L2) -- r7-proven
#define GL2LDS(g, l) __builtin_amdgcn_global_load_lds( \
    (const __attribute__((address_space(1))) void*)(g), \
    (__attribute__((address_space(3))) void*)(l), 16, 0, 16)

__global__ __launch_bounds__(64, 1) void k_gru(
    const bf16* __restrict__ gx,   // [s][b][1536] bf16 (bih already added)
    const bf16* __restrict__ Whh,  // [1536][512] bf16
    const float* __restrict__ bhh, // [1536]
    bf16* __restrict__ hidden)     // [s][b][512] bf16, pre-memset 0xFF
{
  const int lane = threadIdx.x & 63;
  const int c16  = lane & 15, quad = lane >> 4;
  const int pw   = blockIdx.x & 31;     // producer-wave id within group
  const int gb   = blockIdx.x >> 5;     // batch group
  const int hwv  = pw * 16;             // column base
  const int b0   = gb * 8;              // batch base

  __shared__ bf16 wlds[16 * 3 * 64 * 8];  // [kt][gate][lane*8] : 49,152 B
  __shared__ bf16 hp[8 * KP];             // h_prev rows (DMA dest): 8,320 B

  // one-time stage: B-frag for (kt,gate) at this lane = Whh row (g*512+hwv+c16),
  // cols kt*32+quad*8 .. +8  -> stored lane-contiguous (conflict-free)
  for (int g3 = 0; g3 < 3; ++g3)
    for (int kt = 0; kt < 16; ++kt)
      *(short8*)&wlds[((kt*3 + g3)*64 + lane)*8] =
          *(const short8*)&Whh[(long)(g3*512 + hwv + c16)*512 + kt*32 + quad*8];
  const float bhr = bhh[       hwv + c16];
  const float bhz = bhh[ 512 + hwv + c16];
  const float bhn = bhh[1024 + hwv + c16];
  __syncthreads();

  // lane owns output batch rows brv..brv+3 (valid for quad<2; quads 2,3 mirror)
  const int brv = (quad & 1) * 4;

  float gr[4], gz[4], gn[4];
  float hcur[4] = {0.f, 0.f, 0.f, 0.f};   // own cols' h (z*h_prev term), in regs
  { // gx for s=0
    const bf16* gxs = gx + (long)b0 * 1536 + hwv + c16;
#pragma unroll
    for (int i2 = 0; i2 < 4; ++i2) {
      const long ro = (long)(brv + i2) * 1536;
      gr[i2] = __bfloat162float(gxs[ro]);
      gz[i2] = __bfloat162float(gxs[ro + 512]);
      gn[i2] = __bfloat162float(gxs[ro + 1024]);
    }
  }

  for (int s = 0; s < 510; ++s) {
    f32x4 ar = {0.f,0.f,0.f,0.f}, az = {0.f,0.f,0.f,0.f}, an = {0.f,0.f,0.f,0.f};

    if (s > 0) {
      const bf16* src = hidden + ((long)(s-1)*64 + b0)*512 + lane*8;

      // ---- PROBE: row 0 only (1KB DMA + one b128 validate per lane) ----
      // row 0 spans all 512 cols -> one dword from every producer.
      while (true) {
        GL2LDS(src, &hp[0]);   // row 0 -> hp[0..512)
        asm volatile("s_waitcnt vmcnt(0)" ::: "memory");
        union { unsigned u[4]; short8 s8; } pv;
        pv.s8 = *(const short8*)&hp[lane*8];   // 64 lanes x 8 elems = row 0 exact
        unsigned m01 = pv.u[0] > pv.u[1] ? pv.u[0] : pv.u[1];
        unsigned m23 = pv.u[2] > pv.u[3] ? pv.u[2] : pv.u[3];
        unsigned pm = m01 > m23 ? m01 : m23;
        if (__all(pm != 0xFFFFFFFFu)) break;
      }

      // ---- FETCH: full 8KB DMA + full validate (r7's authoritative loop) ----
      union AU { unsigned u[4]; short8 s8; } au[16];
      while (true) {
#pragma unroll
        for (int b = 0; b < 8; ++b) GL2LDS(src + b*512, &hp[b*KP]);
        asm volatile("s_waitcnt vmcnt(0)" ::: "memory");
        unsigned mx = 0u;
#pragma unroll
        for (int kt = 0; kt < 16; ++kt) {
          au[kt].s8 = *(const short8*)&hp[(c16 & 7)*KP + kt*32 + quad*8];
          unsigned m01 = au[kt].u[0] > au[kt].u[1] ? au[kt].u[0] : au[kt].u[1];
          unsigned m23 = au[kt].u[2] > au[kt].u[3] ? au[kt].u[2] : au[kt].u[3];
          unsigned m = m01 > m23 ? m01 : m23;
          mx = mx > m ? mx : m;
        }
        if (__all(mx != 0xFFFFFFFFu)) break;
      }

      // 48 MFMAs, 3 independent chains; A-frags in regs, B from wlds
#pragma unroll
      for (int kt = 0; kt < 16; ++kt) {
        short8 fr = *(const short8*)&wlds[((kt*3 + 0)*64 + lane)*8];
        short8 fz = *(const short8*)&wlds[((kt*3 + 1)*64 + lane)*8];
        short8 fn = *(const short8*)&wlds[((kt*3 + 2)*64 + lane)*8];
        ar = __builtin_amdgcn_mfma_f32_16x16x32_bf16(au[kt].s8, fr, ar, 0, 0, 0);
        az = __builtin_amdgcn_mfma_f32_16x16x32_bf16(au[kt].s8, fz, az, 0, 0, 0);
        an = __builtin_amdgcn_mfma_f32_16x16x32_bf16(au[kt].s8, fn, an, 0, 0, 0);
      }
    }

    // gates + publish (only quad<2 lanes own valid batch rows)
    if (quad < 2) {
#pragma unroll
      for (int i2 = 0; i2 < 4; ++i2) {
        const float r  = 1.0f / (1.0f + expf(-(gr[i2] + ar[i2] + bhr)));
        const float z  = 1.0f / (1.0f + expf(-(gz[i2] + az[i2] + bhz)));
        const float nn = tanhf(gn[i2] + r * (an[i2] + bhn));
        const float hn = (1.0f - z)*nn + z*hcur[i2];
        union { bf16 h; unsigned short u; } cb; cb.h = __float2bfloat16(hn);
        hcur[i2] = __bfloat162float(cb.h);     // exact stored value for next step
        unsigned mine = cb.u;
        unsigned part = (unsigned)__shfl_xor((int)mine, 1, 64);
        if (!(c16 & 1)) {
          unsigned w = (part << 16) | mine;    // lo = col c16, hi = col c16+1
          // device-scope write-through store; dword atomicity = validity granule.
          __hip_atomic_store((unsigned*)(hidden + ((long)s*64 + b0 + brv + i2)*512 + hwv + c16),
                             w, __ATOMIC_RELAXED, __HIP_MEMORY_SCOPE_AGENT);
        }
      }
    }
    if (s < 509) {
      asm volatile("" ::: "memory");  // keep gx prefetch BELOW the stores
      // prefetch gx for s+1 -- latency hides under next step's probe loop
      const bf16* gxs = gx + ((long)(s+1)*64 + b0)*1536 + hwv + c16;
#pragma unroll
      for (int i2 = 0; i2 < 4; ++i2) {
        const long ro = (long)(brv + i2) * 1536;
        gr[i2] = __bfloat162float(gxs[ro]);
        gz[i2] = __bfloat162float(gxs[ro + 512]);
        gn[i2] = __bfloat162float(gxs[ro + 1024]);
      }
    }
  }
}

// ---------------- launch ----------------
extern "C" void kernel_launch(void* const* d_in, const int* in_sizes, int n_in,
                              void* d_out, int out_size, void* d_ws, size_t ws_size,
                              hipStream_t stream)
{
  const float* x    = (const float*)d_in[0];
  const int*   sidx = (const int*)d_in[1];
  const float* sW   = (const float*)d_in[2];
  const float* sb   = (const float*)d_in[3];
  const float* pW   = (const float*)d_in[4];
  const float* pb   = (const float*)d_in[5];
  const float* rsc  = (const float*)d_in[6];
  const float* wih  = (const float*)d_in[7];
  const float* whh  = (const float*)d_in[8];
  const float* bih  = (const float*)d_in[9];
  const float* bhh  = (const float*)d_in[10];
  const float* w1   = (const float*)d_in[11];
  const float* b1   = (const float*)d_in[12];
  const float* w2   = (const float*)d_in[13];
  const float* b2   = (const float*)d_in[14];
  char* ws = (char*)d_ws;
  float* out = (float*)d_out;

  bf16* xbf   = (bf16*)(ws + O_XBF);
  bf16* swbf  = (bf16*)(ws + O_SWB);
  bf16* pwbf  = (bf16*)(ws + O_PW);
  bf16* wihbf = (bf16*)(ws + O_WIH);
  bf16* whhbf = (bf16*)(ws + O_WHH);
  bf16* w1bf  = (bf16*)(ws + O_W1);
  bf16* w2bf  = (bf16*)(ws + O_W2);
  bf16* tokbf = (bf16*)(ws + O_TOK);
  bf16* hbf   = (bf16*)(ws + O_HBF);
  bf16* hidbf = (bf16*)(ws + O_HID);
  bf16* abf   = (bf16*)(ws + O_ABF);
  float* hpre = (float*)(ws + O_GX);  // fp32 h_pre overlaps gx region
  bf16* gxbf  = (bf16*)(ws + O_GX);

  // sentinel-fill hidden: 0xFF dwords are never produced by the GRU (|h|<1)
  hipMemsetAsync(ws + O_HID, 0xFF, HID_BYTES, stream);

  auto cvt = [&](const float* s, bf16* dp, long n) {
    int n4 = (int)(n >> 2);
    k_f2b<<<dim3((n4 + 255) / 256), dim3(256), 0, stream>>>(s, dp, n4);
  };
  cvt(x,   xbf,   (long)B_*T_*D_);
  cvt(sW,  swbf,  16L*128*128);
  cvt(pW,  pwbf,  512L*384);
  cvt(wih, wihbf, 1536L*512);
  cvt(whh, whhbf, 1536L*512);
  cvt(w1,  w1bf,  3L*512*512);
  cvt(w2,  w2bf,  3L*384*512);

  // 1) session align -> tokens (fp32 to d_out [b][n][tok], bf16 to ws rows [n*64+b])
  k_gemm<EPI_TOK><<<dim3(4, 1, 64), dim3(256), 0, stream>>>(
      xbf, swbf, sb, nullptr, 128, 0,
      (long)T_*D_, 128L*128, 128L, 0L, sidx, out + TOKOFF_, tokbf);

  // 2) proj: h_pre = tokens @ proj_W^T + b  (fp32, rows [n*64+b])
  k_gemm<EPI_F32><<<dim3(255, 4, 1), dim3(256), 0, stream>>>(
      tokbf, pwbf, pb, hpre, 384, 512, 0, 0, 0, 0, nullptr, nullptr, nullptr);

  // 3) RMSNorm -> h bf16
  k_rms<<<dim3(8160), dim3(256), 0, stream>>>(hpre, rsc, hbf);

  // 4) gx = h @ Wih^T + bih  (bf16, rows [n*64+b] == [s][b][1536])
  k_gemm<EPI_BF16><<<dim3(255, 12, 1), dim3(256), 0, stream>>>(
      hbf, wihbf, bih, gxbf, 512, 1536, 0, 0, 0, 0, nullptr, nullptr, nullptr);

  // 5) GRU scan: 8 groups x 32 single-wave WGs = 256 WGs x 64 thr (1 wave/CU).
  //    Flagless sentinel protocol with probe-then-fetch detect.
  k_gru<<<dim3(256), dim3(64), 0, stream>>>(gxbf, whhbf, bhh, hidbf);

  // 6) heads: a = gelu(hidden @ W1^T + b1); preds = a @ W2^T + b2 (remap rows)
  for (int k = 0; k < 3; ++k) {
    k_gemm<EPI_GELU><<<dim3(255, 4, 1), dim3(256), 0, stream>>>(
        hidbf, w1bf + (long)k*512*512, b1 + (long)k*512, abf,
        512, 512, 0, 0, 0, 0, nullptr, nullptr, nullptr);
    k_gemm<EPI_F32R><<<dim3(255, 3, 1), dim3(256), 0, stream>>>(
        abf, w2bf + (long)k*384*512, b2 + (long)k*384, out + (long)k*PRED1_,
        512, 384, 0, 0, 0, 0, nullptr, nullptr, nullptr);
  }
}

// Round 12
// 2113.632 us; speedup vs baseline: 1.7065x; 1.0837x over previous
//
#include <hip/hip_runtime.h>
#include <hip/hip_bf16.h>
#include <math.h>

typedef __hip_bfloat16 bf16;
typedef __attribute__((ext_vector_type(8))) short short8;
typedef __attribute__((ext_vector_type(4))) short short4v;
typedef __attribute__((ext_vector_type(4))) float f32x4;

// problem dims
#define B_    64
#define T_    512
#define D_    128
#define N_    510
#define H_    512
#define TOK_  384
#define PRED1_ 12533760L  // B_*N_*TOK_
#define TOKOFF_ 37601280L // 3*PRED1_ : tokens offset in d_out (floats)

// ---- workspace layout (bytes) ----
#define O_XBF  0UL            // x bf16            8,388,608
#define O_SWB  8388608UL      // sess_W bf16         524,288
#define O_PW   8912896UL      // proj_W bf16         393,216
#define O_WIH  9306112UL      // gru_Wih bf16      1,572,864
#define O_WHH  10878976UL     // gru_Whh bf16      1,572,864
#define O_W1   12451840UL     // head_W1 bf16      1,572,864
#define O_W2   14024704UL     // head_W2 bf16      1,179,648
#define O_TOK  15204352UL     // tokens bf16      25,067,520  rows [n*64+b]
#define O_HBF  40271872UL     // h bf16 (post-RMS)33,423,360
#define O_HID  73695232UL     // hidden bf16      33,423,360  rows [s*64+b]
#define O_ABF  107118592UL    // gelu act bf16
#define O_GX   140541952UL    // gx bf16 100,270,080 (h_pre fp32 overlapped first)

#define HID_BYTES 33423360UL

// ---------------- fp32 -> bf16 convert ----------------
__global__ void k_f2b(const float* __restrict__ s, bf16* __restrict__ d, int n4) {
  int i = blockIdx.x * 256 + threadIdx.x;
  if (i < n4) {
    float4 v = ((const float4*)s)[i];
    union { short4v sv; bf16 h[4]; } u;
    u.h[0] = __float2bfloat16(v.x); u.h[1] = __float2bfloat16(v.y);
    u.h[2] = __float2bfloat16(v.z); u.h[3] = __float2bfloat16(v.w);
    ((short4v*)d)[i] = u.sv;
  }
}

// ---------------- generic bf16 MFMA GEMM: C = A[M,K] @ W[N,K]^T + bias ----------------
enum { EPI_F32 = 0, EPI_BF16 = 1, EPI_GELU = 2, EPI_TOK = 3, EPI_F32R = 4 };
#define SLDA 40

template <int EPI>
__global__ __launch_bounds__(256, 2) void k_gemm(
    const bf16* __restrict__ A, const bf16* __restrict__ W,
    const float* __restrict__ bias, void* __restrict__ C,
    int K, int ldc, long zA, long zW, long zB, long zC,
    const int* __restrict__ sidx, float* __restrict__ tokf, bf16* __restrict__ tokb)
{
  const int tid = threadIdx.x;
  const int bm = blockIdx.x, bn = blockIdx.y, z = blockIdx.z;
  const int wsel = (EPI == EPI_TOK) ? sidx[z] : z;
  const int lane = tid & 63, wave = tid >> 6;
  const int wm = (wave & 1) << 6, wn = (wave >> 1) << 6;
  const int r16 = lane & 15, quad = lane >> 4;

  __shared__ bf16 sA[128 * SLDA];
  __shared__ bf16 sB[128 * SLDA];

  const bf16* Ag = A + (long)z * zA + (long)bm * 128 * K;
  const bf16* Wg = W + (long)wsel * zW + (long)bn * 128 * K;

  f32x4 zf = {0.f, 0.f, 0.f, 0.f};
  f32x4 acc[4][4];
  for (int i = 0; i < 4; ++i) for (int j = 0; j < 4; ++j) acc[i][j] = zf;

  const int sr = tid >> 1, sc = (tid & 1) << 4;
  for (int k0 = 0; k0 < K; k0 += 32) {
    *(short8*)&sA[sr*SLDA + sc]     = *(const short8*)&Ag[(long)sr*K + k0 + sc];
    *(short8*)&sA[sr*SLDA + sc + 8] = *(const short8*)&Ag[(long)sr*K + k0 + sc + 8];
    *(short8*)&sB[sr*SLDA + sc]     = *(const short8*)&Wg[(long)sr*K + k0 + sc];
    *(short8*)&sB[sr*SLDA + sc + 8] = *(const short8*)&Wg[(long)sr*K + k0 + sc + 8];
    __syncthreads();
    short8 fa[4], fb[4];
    for (int i = 0; i < 4; ++i) fa[i] = *(const short8*)&sA[(wm + i*16 + r16)*SLDA + quad*8];
    for (int j = 0; j < 4; ++j) fb[j] = *(const short8*)&sB[(wn + j*16 + r16)*SLDA + quad*8];
    for (int i = 0; i < 4; ++i)
      for (int j = 0; j < 4; ++j)
        acc[i][j] = __builtin_amdgcn_mfma_f32_16x16x32_bf16(fa[i], fb[j], acc[i][j], 0, 0, 0);
    __syncthreads();
  }

  const float* bz = bias + (long)wsel * zB + bn * 128;
  for (int i = 0; i < 4; ++i) {
    for (int j = 0; j < 4; ++j) {
      const int colL = wn + j*16 + r16;
      const float bv = bz[colL];
      for (int r = 0; r < 4; ++r) {
        float v = acc[i][j][r] + bv;
        const long grow = (long)bm*128 + wm + i*16 + quad*4 + r;
        const long gcol = (long)bn*128 + colL;
        if (EPI == EPI_F32) {
          ((float*)C)[(long)z*zC + grow*ldc + gcol] = v;
        } else if (EPI == EPI_BF16) {
          ((bf16*)C)[(long)z*zC + grow*ldc + gcol] = __float2bfloat16(v);
        } else if (EPI == EPI_GELU) {
          v = 0.5f * v * (1.0f + erff(v * 0.70710678118654752f));
          ((bf16*)C)[(long)z*zC + grow*ldc + gcol] = __float2bfloat16(v);
        } else if (EPI == EPI_F32R) {
          // rows are [n*64+b]; output wants [b*510+n]
          const long rb = grow & 63, rn = grow >> 6;
          ((float*)C)[(rb*510 + rn)*ldc + gcol] = v;
        } else { // EPI_TOK: z=batch, grow=t, gcol=e
          for (int p = 0; p < 3; ++p) {
            long n = grow - p;
            if (n >= 0 && n < N_) {
              tokf[((long)z*N_ + n)*TOK_ + gcol*3 + p] = v;                 // d_out: [b][n][tok]
              tokb[((long)n*B_ + z)*TOK_ + gcol*3 + p] = __float2bfloat16(v); // ws: rows [n*64+b]
            }
          }
        }
      }
    }
  }
}

// ---------------- RMSNorm rows of 512: fp32 in -> bf16 out ----------------
__global__ __launch_bounds__(256) void k_rms(const float* __restrict__ hpre,
                                             const float* __restrict__ scale,
                                             bf16* __restrict__ hbf)
{
  const int wave = threadIdx.x >> 6, lane = threadIdx.x & 63;
  const long row = (long)blockIdx.x * 4 + wave;
  const float* p = hpre + row * 512 + lane * 8;
  float4 v0 = *(const float4*)p;
  float4 v1 = *(const float4*)(p + 4);
  float ss = v0.x*v0.x + v0.y*v0.y + v0.z*v0.z + v0.w*v0.w
           + v1.x*v1.x + v1.y*v1.y + v1.z*v1.z + v1.w*v1.w;
  for (int m = 32; m >= 1; m >>= 1) ss += __shfl_xor(ss, m, 64);
  const float inv = 1.0f / sqrtf(ss * (1.0f/512.0f) + 1e-6f);
  const float* sc = scale + lane * 8;
  union { short8 sv; bf16 h[8]; } u;
  u.h[0] = __float2bfloat16(v0.x*inv*sc[0]); u.h[1] = __float2bfloat16(v0.y*inv*sc[1]);
  u.h[2] = __float2bfloat16(v0.z*inv*sc[2]); u.h[3] = __float2bfloat16(v0.w*inv*sc[3]);
  u.h[4] = __float2bfloat16(v1.x*inv*sc[4]); u.h[5] = __float2bfloat16(v1.y*inv*sc[5]);
  u.h[6] = __float2bfloat16(v1.z*inv*sc[6]); u.h[7] = __float2bfloat16(v1.w*inv*sc[7]);
  *(short8*)(hbf + row * 512 + lane * 8) = u.sv;
}

// ---------------- GRU: flagless self-certifying persistent scan (r7 champion) ----------------
// 8 independent batch-groups of 8 batches; per group 32 single-wave WGs
// (grid 256 x 64 thr, 1 wave/CU). Wave pw owns cols [16pw,16pw+16), all 3 gates.
// Sentinel protocol: |h| < 1 strictly, so a stored dword (2 packed bf16) can
// never be 0xFFFFFFFF. hidden[] is pre-memset to 0xFF. Producers just store
// (no ack, no flag). Consumers speculatively DMA h[s-1] (8 coalesced 1KB sc1
// bursts), load A-frags (needed anyway), and validate by max-accumulating
// their 64 dwords: any 0xFFFFFFFF -> re-DMA. Dword stores are atomic, so any
// store order is safe; every dword consumed is individually checked.
// No deadlock: the group-minimum-step wave always has all deps written.
// FLOOR NOTE (r8-r11): L2-local fast path hung; SW-pipelining 2 groups/wave
// +100% (retry vmcnt(0) drains sister DMA); 3-wave gate-split +22% (compute
// not the bottleneck); probe-then-fetch +10% (detect is producer-bound).
// Step = ~7200cy: ~1500 compute + ~5700 serial cross-CU transit/straggle --
// the structural floor of a 510-step chained recurrence at 1 wave/CU.
#define KP 520   // LDS row pad (elems)

// aux=16 == CPol SC1 on gfx950: device-scope load (coherent past L2)
#define GL2LDS(g, l) __builtin_amdgcn_global_load_lds( \
    (const __attribute__((address_space(1))) void*)(g), \
    (__attribute__((address_space(3))) void*)(l), 16, 0, 16)

__global__ __launch_bounds__(64, 1) void k_gru(
    const bf16* __restrict__ gx,   // [s][b][1536] bf16 (bih already added)
    const bf16* __restrict__ Whh,  // [1536][512] bf16
    const float* __restrict__ bhh, // [1536]
    bf16* __restrict__ hidden)     // [s][b][512] bf16, pre-memset 0xFF
{
  const int lane = threadIdx.x & 63;
  const int c16  = lane & 15, quad = lane >> 4;
  const int pw   = blockIdx.x & 31;     // producer-wave id within group
  const int gb   = blockIdx.x >> 5;     // batch group
  const int hwv  = pw * 16;             // column base
  const int b0   = gb * 8;              // batch base

  __shared__ bf16 wlds[16 * 3 * 64 * 8];  // [kt][gate][lane*8] : 49,152 B
  __shared__ bf16 hp[8 * KP];             // h_prev rows (DMA dest): 8,320 B

  // one-time stage: B-frag for (kt,gate) at this lane = Whh row (g*512+hwv+c16),
  // cols kt*32+quad*8 .. +8  -> stored lane-contiguous (conflict-free)
  for (int g3 = 0; g3 < 3; ++g3)
    for (int kt = 0; kt < 16; ++kt)
      *(short8*)&wlds[((kt*3 + g3)*64 + lane)*8] =
          *(const short8*)&Whh[(long)(g3*512 + hwv + c16)*512 + kt*32 + quad*8];
  const float bhr = bhh[       hwv + c16];
  const float bhz = bhh[ 512 + hwv + c16];
  const float bhn = bhh[1024 + hwv + c16];
  __syncthreads();

  // lane owns output batch rows brv..brv+3 (valid for quad<2; quads 2,3 mirror)
  const int brv = (quad & 1) * 4;

  float gr[4], gz[4], gn[4];
  float hcur[4] = {0.f, 0.f, 0.f, 0.f};   // own cols' h (z*h_prev term), in regs
  { // gx for s=0
    const bf16* gxs = gx + (long)b0 * 1536 + hwv + c16;
#pragma unroll
    for (int i2 = 0; i2 < 4; ++i2) {
      const long ro = (long)(brv + i2) * 1536;
      gr[i2] = __bfloat162float(gxs[ro]);
      gz[i2] = __bfloat162float(gxs[ro + 512]);
      gn[i2] = __bfloat162float(gxs[ro + 1024]);
    }
  }

  for (int s = 0; s < 510; ++s) {
    f32x4 ar = {0.f,0.f,0.f,0.f}, az = {0.f,0.f,0.f,0.f}, an = {0.f,0.f,0.f,0.f};

    if (s > 0) {
      // speculative DMA + validate-retry: the DMA IS the poll.
      union AU { unsigned u[4]; short8 s8; } au[16];
      const bf16* src = hidden + ((long)(s-1)*64 + b0)*512 + lane*8;
      while (true) {
#pragma unroll
        for (int b = 0; b < 8; ++b) GL2LDS(src + b*512, &hp[b*KP]);
        asm volatile("s_waitcnt vmcnt(0)" ::: "memory");  // DMA landed in hp
        // A-frag loads double as validation reads
        unsigned mx = 0u;
#pragma unroll
        for (int kt = 0; kt < 16; ++kt) {
          au[kt].s8 = *(const short8*)&hp[(c16 & 7)*KP + kt*32 + quad*8];
          unsigned m01 = au[kt].u[0] > au[kt].u[1] ? au[kt].u[0] : au[kt].u[1];
          unsigned m23 = au[kt].u[2] > au[kt].u[3] ? au[kt].u[2] : au[kt].u[3];
          unsigned m = m01 > m23 ? m01 : m23;
          mx = mx > m ? mx : m;
        }
        // legit dwords are two bf16 of |h|<1 -> each half <= 0xBF7F -> never all-ones
        if (__all(mx != 0xFFFFFFFFu)) break;
      }

      // 48 MFMAs, 3 independent chains; A-frags already in regs, B from wlds
#pragma unroll
      for (int kt = 0; kt < 16; ++kt) {
        short8 fr = *(const short8*)&wlds[((kt*3 + 0)*64 + lane)*8];
        short8 fz = *(const short8*)&wlds[((kt*3 + 1)*64 + lane)*8];
        short8 fn = *(const short8*)&wlds[((kt*3 + 2)*64 + lane)*8];
        ar = __builtin_amdgcn_mfma_f32_16x16x32_bf16(au[kt].s8, fr, ar, 0, 0, 0);
        az = __builtin_amdgcn_mfma_f32_16x16x32_bf16(au[kt].s8, fz, az, 0, 0, 0);
        an = __builtin_amdgcn_mfma_f32_16x16x32_bf16(au[kt].s8, fn, an, 0, 0, 0);
      }
    }

    // gates + publish (only quad<2 lanes own valid batch rows)
    if (quad < 2) {
#pragma unroll
      for (int i2 = 0; i2 < 4; ++i2) {
        const float r  = 1.0f / (1.0f + expf(-(gr[i2] + ar[i2] + bhr)));
        const float z  = 1.0f / (1.0f + expf(-(gz[i2] + az[i2] + bhz)));
        const float nn = tanhf(gn[i2] + r * (an[i2] + bhn));
        const float hn = (1.0f - z)*nn + z*hcur[i2];
        union { bf16 h; unsigned short u; } cb; cb.h = __float2bfloat16(hn);
        hcur[i2] = __bfloat162float(cb.h);     // exact stored value for next step
        unsigned mine = cb.u;
        unsigned part = (unsigned)__shfl_xor((int)mine, 1, 64);
        if (!(c16 & 1)) {
          unsigned w = (part << 16) | mine;    // lo = col c16, hi = col c16+1
          // device-scope write-through store; dword atomicity = validity granule.
          // No ack, no flag: consumers self-validate against the 0xFF sentinel.
          __hip_atomic_store((unsigned*)(hidden + ((long)s*64 + b0 + brv + i2)*512 + hwv + c16),
                             w, __ATOMIC_RELAXED, __HIP_MEMORY_SCOPE_AGENT);
        }
      }
    }
    if (s < 509) {
      asm volatile("" ::: "memory");  // keep gx prefetch BELOW the stores
      // prefetch gx for s+1 -- latency hides under next step's DMA/validate
      const bf16* gxs = gx + ((long)(s+1)*64 + b0)*1536 + hwv + c16;
#pragma unroll
      for (int i2 = 0; i2 < 4; ++i2) {
        const long ro = (long)(brv + i2) * 1536;
        gr[i2] = __bfloat162float(gxs[ro]);
        gz[i2] = __bfloat162float(gxs[ro + 512]);
        gn[i2] = __bfloat162float(gxs[ro + 1024]);
      }
    }
  }
}

// ---------------- launch ----------------
extern "C" void kernel_launch(void* const* d_in, const int* in_sizes, int n_in,
                              void* d_out, int out_size, void* d_ws, size_t ws_size,
                              hipStream_t stream)
{
  const float* x    = (const float*)d_in[0];
  const int*   sidx = (const int*)d_in[1];
  const float* sW   = (const float*)d_in[2];
  const float* sb   = (const float*)d_in[3];
  const float* pW   = (const float*)d_in[4];
  const float* pb   = (const float*)d_in[5];
  const float* rsc  = (const float*)d_in[6];
  const float* wih  = (const float*)d_in[7];
  const float* whh  = (const float*)d_in[8];
  const float* bih  = (const float*)d_in[9];
  const float* bhh  = (const float*)d_in[10];
  const float* w1   = (const float*)d_in[11];
  const float* b1   = (const float*)d_in[12];
  const float* w2   = (const float*)d_in[13];
  const float* b2   = (const float*)d_in[14];
  char* ws = (char*)d_ws;
  float* out = (float*)d_out;

  bf16* xbf   = (bf16*)(ws + O_XBF);
  bf16* swbf  = (bf16*)(ws + O_SWB);
  bf16* pwbf  = (bf16*)(ws + O_PW);
  bf16* wihbf = (bf16*)(ws + O_WIH);
  bf16* whhbf = (bf16*)(ws + O_WHH);
  bf16* w1bf  = (bf16*)(ws + O_W1);
  bf16* w2bf  = (bf16*)(ws + O_W2);
  bf16* tokbf = (bf16*)(ws + O_TOK);
  bf16* hbf   = (bf16*)(ws + O_HBF);
  bf16* hidbf = (bf16*)(ws + O_HID);
  bf16* abf   = (bf16*)(ws + O_ABF);
  float* hpre = (float*)(ws + O_GX);  // fp32 h_pre overlaps gx region
  bf16* gxbf  = (bf16*)(ws + O_GX);

  // sentinel-fill hidden: 0xFF bytes = bf16 -NaN dwords, never produced by the GRU
  hipMemsetAsync(ws + O_HID, 0xFF, HID_BYTES, stream);

  auto cvt = [&](const float* s, bf16* dp, long n) {
    int n4 = (int)(n >> 2);
    k_f2b<<<dim3((n4 + 255) / 256), dim3(256), 0, stream>>>(s, dp, n4);
  };
  cvt(x,   xbf,   (long)B_*T_*D_);
  cvt(sW,  swbf,  16L*128*128);
  cvt(pW,  pwbf,  512L*384);
  cvt(wih, wihbf, 1536L*512);
  cvt(whh, whhbf, 1536L*512);
  cvt(w1,  w1bf,  3L*512*512);
  cvt(w2,  w2bf,  3L*384*512);

  // 1) session align -> tokens (fp32 to d_out [b][n][tok], bf16 to ws rows [n*64+b])
  k_gemm<EPI_TOK><<<dim3(4, 1, 64), dim3(256), 0, stream>>>(
      xbf, swbf, sb, nullptr, 128, 0,
      (long)T_*D_, 128L*128, 128L, 0L, sidx, out + TOKOFF_, tokbf);

  // 2) proj: h_pre = tokens @ proj_W^T + b  (fp32, rows [n*64+b])
  k_gemm<EPI_F32><<<dim3(255, 4, 1), dim3(256), 0, stream>>>(
      tokbf, pwbf, pb, hpre, 384, 512, 0, 0, 0, 0, nullptr, nullptr, nullptr);

  // 3) RMSNorm -> h bf16
  k_rms<<<dim3(8160), dim3(256), 0, stream>>>(hpre, rsc, hbf);

  // 4) gx = h @ Wih^T + bih  (bf16, rows [n*64+b] == [s][b][1536])
  k_gemm<EPI_BF16><<<dim3(255, 12, 1), dim3(256), 0, stream>>>(
      hbf, wihbf, bih, gxbf, 512, 1536, 0, 0, 0, 0, nullptr, nullptr, nullptr);

  // 5) GRU scan: 8 groups x 32 single-wave WGs = 256 WGs x 64 thr (1 wave/CU).
  //    Flagless: correctness carried by the 0xFF sentinel pre-fill above.
  k_gru<<<dim3(256), dim3(64), 0, stream>>>(gxbf, whhbf, bhh, hidbf);

  // 6) heads: a = gelu(hidden @ W1^T + b1); preds = a @ W2^T + b2 (remap rows)
  for (int k = 0; k < 3; ++k) {
    k_gemm<EPI_GELU><<<dim3(255, 4, 1), dim3(256), 0, stream>>>(
        hidbf, w1bf + (long)k*512*512, b1 + (long)k*512, abf,
        512, 512, 0, 0, 0, 0, nullptr, nullptr, nullptr);
    k_gemm<EPI_F32R><<<dim3(255, 3, 1), dim3(256), 0, stream>>>(
        abf, w2bf + (long)k*384*512, b2 + (long)k*384, out + (long)k*PRED1_,
        512, 384, 0, 0, 0, 0, nullptr, nullptr, nullptr);
  }
}